// Round 12
// baseline (562.367 us; speedup 1.0000x reference)
//
#include <hip/hip_runtime.h>

#define NMAT 2048
#define KATTR 64
#define CAP 64
#define NITER 10
#define SENT_A 2048  // Phase A sentinel: extra zeroed row of M buffers
#define SENT_B 2057  // Phase B sentinel: swz(2057)=8232, outside real swz image

typedef unsigned short ushort4v __attribute__((ext_vector_type(4)));

__device__ __forceinline__ unsigned short f2bf(float f) {
  unsigned u = __float_as_uint(f);
  return (unsigned short)((u + 0x7fff + ((u >> 16) & 1)) >> 16);
}
__device__ __forceinline__ float bf2f(unsigned short b) {
  return __uint_as_float((unsigned)b << 16);
}
__device__ __forceinline__ float bflo(unsigned v) {
  return __uint_as_float(v << 16);
}
__device__ __forceinline__ float bfhi(unsigned v) {
  return __uint_as_float(v & 0xffff0000u);
}
// swizzled LDS dword index (proven v3/v5/v7)
__device__ __forceinline__ int swz(int c) { return 4 * c + (((c >> 3) & 7) << 2); }

// --------------------------------------------------------------------------
// DETERMINISTIC build: count -> scan -> write in ascending column order.
// Grid 2*NMAT: b < NMAT: A1 row (no idxT4); b >= NMAT: A2 row (+ idxT4).
// --------------------------------------------------------------------------
__global__ __launch_bounds__(256) void k_build2(
    const float* __restrict__ A1, const float* __restrict__ A2,
    unsigned short* __restrict__ idx1, unsigned short* __restrict__ idx2,
    unsigned short* __restrict__ idxT4, int* __restrict__ cnt1,
    int* __restrict__ cnt2) {
  __shared__ int wsum[4];
  int b = blockIdx.x;
  const float* A;
  unsigned short* idx;
  unsigned short* idxT;
  int* cnt;
  int r;
  if (b < NMAT) {
    A = A1; idx = idx1; idxT = nullptr; cnt = cnt1; r = b;
  } else {
    A = A2; idx = idx2; idxT = idxT4; cnt = cnt2; r = b - NMAT;
  }
  const float* row = A + (size_t)r * NMAT;
  int t = threadIdx.x;
  unsigned mask = 0;
  int ln = 0;
#pragma unroll
  for (int u = 0; u < 8; ++u) {
    int c = t * 8 + u;
    if (row[c] != 0.0f) {
      mask |= 1u << u;
      ++ln;
    }
  }
  int lane = t & 63, wv = t >> 6;
  int v = ln;
  for (int o = 1; o < 64; o <<= 1) {
    int x = __shfl_up(v, o);
    if (lane >= o) v += x;
  }
  if (lane == 63) wsum[wv] = v;
  __syncthreads();
  int base = 0, stot = 0;
#pragma unroll
  for (int w = 0; w < 4; ++w) {
    int x = wsum[w];
    if (w < wv) base += x;
    stot += x;
  }
  int off = base + v - ln;
#pragma unroll
  for (int u = 0; u < 8; ++u) {
    if (mask & (1u << u)) {
      int c = t * 8 + u;
      if (off < CAP) {
        idx[r * CAP + off] = (unsigned short)c;
        if (idxT)
          idxT[(size_t)(off >> 2) * (NMAT * 4) + r * 4 + (off & 3)] =
              (unsigned short)c;
      }
      ++off;
    }
  }
  int n = stot < CAP ? stot : CAP;
  for (int p = n + t; p < CAP; p += 256) {
    idx[r * CAP + p] = (unsigned short)SENT_A;
    if (idxT)
      idxT[(size_t)(p >> 2) * (NMAT * 4) + r * 4 + (p & 3)] =
          (unsigned short)SENT_B;
  }
  if (t == 0) cnt[r] = n;
}

// Row-l2-normalize N1 and N2 in one launch (grid 2*(NMAT/4)).
__global__ __launch_bounds__(256) void k_norm2(const float* __restrict__ N1,
                                               const float* __restrict__ N2,
                                               float* __restrict__ N1n,
                                               float* __restrict__ N2n) {
  int half = blockIdx.x >= (NMAT / 4);
  const float* Nin = half ? N2 : N1;
  float* Nout = half ? N2n : N1n;
  int bb = half ? blockIdx.x - NMAT / 4 : blockIdx.x;
  int row = bb * 4 + (threadIdx.x >> 6);
  int lane = threadIdx.x & 63;
  float v = Nin[(size_t)row * KATTR + lane];
  float ss = v * v;
#pragma unroll
  for (int o = 32; o > 0; o >>= 1) ss += __shfl_xor(ss, o);
  float nrm = sqrtf(ss);
  Nout[(size_t)row * KATTR + lane] = (nrm > 0.f) ? v / nrm : 0.f;
}

// C1 = pattern(A1) @ N1n and C2 = pattern(A2) @ N2n in one launch.
__global__ void k_gatherN2(const unsigned short* __restrict__ idx1,
                           const int* __restrict__ cnt1,
                           const float* __restrict__ N1n,
                           float* __restrict__ C1,
                           const unsigned short* __restrict__ idx2,
                           const int* __restrict__ cnt2,
                           const float* __restrict__ N2n,
                           float* __restrict__ C2) {
  int half = blockIdx.x >= NMAT;
  const unsigned short* idx = half ? idx2 : idx1;
  const int* cnt = half ? cnt2 : cnt1;
  const float* Nn = half ? N2n : N1n;
  float* C = half ? C2 : C1;
  int i = half ? blockIdx.x - NMAT : blockIdx.x;
  int lane = threadIdx.x;  // blockDim = 64
  int nn = cnt[i];
  const unsigned short* ip = idx + i * CAP;
  float acc = 0.f;
  for (int t = 0; t < nn; ++t) {
    int k = ip[t];
    acc += Nn[(size_t)k * KATTR + lane];
  }
  C[(size_t)i * KATTR + lane] = acc;
}

// Zero the sentinel row (row 2048) of the gather buffers, once.
__global__ __launch_bounds__(1024) void k_zrow(unsigned short* __restrict__ Mb0,
                                               unsigned short* __restrict__ Mb1,
                                               float* __restrict__ Mf) {
  size_t Z = (size_t)NMAT * NMAT;
  for (int o = threadIdx.x; o < NMAT; o += 1024) {
    Mb0[Z + o] = 0;
    Mb1[Z + o] = 0;
    Mf[Z + o] = 0.f;
  }
}

// --------------------------------------------------------------------------
// q = Nm>0&dm>0 ? Nm*rsqrt(Nm*dm) : 0.   (H-transpose fused through LDS;
// also emits Ht for the last-iteration fp32 epilogue.)
// Outputs: M0gather = bf16(q*Ht), q (fp32), Ht (fp32),
// QM = pack(bf16(alpha*q^2) | bf16((1-a)*q*Ht) << 16)  (iters 0..8).
// --------------------------------------------------------------------------
__global__ __launch_bounds__(256) void k_q(
    const float* __restrict__ N1n, const float* __restrict__ C1,
    const float* __restrict__ N2n, const float* __restrict__ C2,
    const float* __restrict__ H, float* __restrict__ q,
    unsigned* __restrict__ QM, unsigned short* __restrict__ M,
    float* __restrict__ Ht) {
  __shared__ float sA[64][68];
  __shared__ float sB[64][68];
  int i0 = blockIdx.y * 64, j0 = blockIdx.x * 64;
  int c = threadIdx.x & 63, r0 = threadIdx.x >> 6;
  int tx = threadIdx.x & 15, ty = threadIdx.x >> 4;
  const float alpha = 0.82f;

  float nmv[4][4] = {};
  float dmv[4][4] = {};

  for (int r = r0; r < 64; r += 4) {
    sA[c][r] = N1n[(size_t)(i0 + r) * KATTR + c];
    sB[c][r] = N2n[(size_t)(j0 + r) * KATTR + c];
  }
  __syncthreads();
#pragma unroll 4
  for (int k = 0; k < 64; ++k) {
    float4 a = *(const float4*)&sA[k][ty * 4];
    float4 b = *(const float4*)&sB[k][tx * 4];
    float av[4] = {a.x, a.y, a.z, a.w};
    float bv[4] = {b.x, b.y, b.z, b.w};
#pragma unroll
    for (int ii = 0; ii < 4; ++ii)
#pragma unroll
      for (int jj = 0; jj < 4; ++jj)
        nmv[ii][jj] = fmaf(av[ii], bv[jj], nmv[ii][jj]);
  }
  __syncthreads();
  for (int r = r0; r < 64; r += 4) {
    sA[c][r] = C1[(size_t)(i0 + r) * KATTR + c];
    sB[c][r] = C2[(size_t)(j0 + r) * KATTR + c];
  }
  __syncthreads();
#pragma unroll 4
  for (int k = 0; k < 64; ++k) {
    float4 a = *(const float4*)&sA[k][ty * 4];
    float4 b = *(const float4*)&sB[k][tx * 4];
    float av[4] = {a.x, a.y, a.z, a.w};
    float bv[4] = {b.x, b.y, b.z, b.w};
#pragma unroll
    for (int ii = 0; ii < 4; ++ii)
#pragma unroll
      for (int jj = 0; jj < 4; ++jj)
        dmv[ii][jj] = fmaf(av[ii], bv[jj], dmv[ii][jj]);
  }
  __syncthreads();
  // fused transpose: sA[i_local][j_local] = H[(j0+j_local)*NMAT + i0+i_local]
  for (int r = r0; r < 64; r += 4)
    sA[c][r] = H[(size_t)(j0 + r) * NMAT + i0 + c];
  __syncthreads();

#pragma unroll
  for (int ii = 0; ii < 4; ++ii) {
    int i = i0 + ty * 4 + ii;
    size_t base = (size_t)i * NMAT + j0 + tx * 4;
    float4 hv = *(const float4*)&sA[ty * 4 + ii][tx * 4];
    float hvv[4] = {hv.x, hv.y, hv.z, hv.w};
    float qv[4];
    unsigned qmv[4];
    ushort4v mv;
#pragma unroll
    for (int jj = 0; jj < 4; ++jj) {
      float nmx = nmv[ii][jj];
      float D = nmx * dmv[ii][jj];
      float qq = (D > 0.f) ? nmx * rsqrtf(D) : 0.f;
      qv[jj] = qq;
      float m0 = qq * hvv[jj];
      mv[jj] = f2bf(m0);
      qmv[jj] = (unsigned)f2bf(alpha * qq * qq) |
                ((unsigned)f2bf((1.0f - alpha) * m0) << 16);
    }
    *(float4*)&q[base] = make_float4(qv[0], qv[1], qv[2], qv[3]);
    *(uint4*)&QM[base] = make_uint4(qmv[0], qmv[1], qmv[2], qmv[3]);
    *(ushort4v*)&M[base] = mv;
    *(float4*)&Ht[base] = hv;
  }
}

// --------------------------------------------------------------------------
// Phase A (v13): T1 = pattern(A1)^T-gather of M, column-chunked + XCD-pinned.
// Grid 512: chunk = blockIdx&7 (-> XCD via round-robin dispatch), tile =
// blockIdx>>3. Block covers 32 rows x 256 cols. All 64 blocks of chunk c
// gather ONLY from M[:, c*256 .. c*256+255] -- a 1 MB bf16 slice (2 MB fp32)
// that fits the 4 MB per-XCD L2, so the deg-fold re-reads (the 119 MB/iter
// FETCH in v12) become L2 hits. T1 written fp32 non-temporal (keeps slice
// resident). Per-element fp32 accumulation order identical to v12.
// --------------------------------------------------------------------------
__global__ __launch_bounds__(1024, 8) void k_phA(
    const unsigned short* __restrict__ idx1, const int* __restrict__ cnt1,
    const unsigned short* __restrict__ Min, const float* __restrict__ MinF,
    float* __restrict__ T1, int in32) {
  int b = blockIdx.x;
  int chunk = b & 7, tile = b >> 3;
  int tid = threadIdx.x;
  int rg = tid >> 7;       // row group 0..7 (4 rows each)
  int l = tid & 127;       // lane in group
  int jbase = chunk * 256 + l * 2;  // this thread's 2 columns
  int irow0 = tile * 32 + rg * 4;

#pragma unroll
  for (int rr = 0; rr < 4; ++rr) {
    int i = irow0 + rr;
    int nn = cnt1[i];
    const unsigned short* ip = idx1 + i * CAP;
    uint4 pA = *(const uint4*)(ip);
    uint4 pB = *(const uint4*)(ip + 8);
    uint4 pC = *(const uint4*)(ip + 16);
    uint4 pD = *(const uint4*)(ip + 24);
    float a0 = 0.f, a1 = 0.f;
    if (in32) {
      const float* Bf = MinF + jbase;
      auto g8f = [&](uint4 pk, float2* w) {
        w[0] = *(const float2*)(Bf + (size_t)(pk.x & 0xffff) * NMAT);
        w[1] = *(const float2*)(Bf + (size_t)(pk.x >> 16) * NMAT);
        w[2] = *(const float2*)(Bf + (size_t)(pk.y & 0xffff) * NMAT);
        w[3] = *(const float2*)(Bf + (size_t)(pk.y >> 16) * NMAT);
        w[4] = *(const float2*)(Bf + (size_t)(pk.z & 0xffff) * NMAT);
        w[5] = *(const float2*)(Bf + (size_t)(pk.z >> 16) * NMAT);
        w[6] = *(const float2*)(Bf + (size_t)(pk.w & 0xffff) * NMAT);
        w[7] = *(const float2*)(Bf + (size_t)(pk.w >> 16) * NMAT);
      };
      float2 w[16];
      g8f(pA, w);
      g8f(pB, w + 8);
#pragma unroll
      for (int e = 0; e < 16; ++e) {
        a0 += w[e].x;
        a1 += w[e].y;
      }
      if (nn > 16) {
        float2 w2[16];
        g8f(pC, w2);
        g8f(pD, w2 + 8);
#pragma unroll
        for (int e = 0; e < 16; ++e) {
          a0 += w2[e].x;
          a1 += w2[e].y;
        }
      }
      for (int t = 32; t < nn; t += 8) {
        uint4 pk = *(const uint4*)(ip + t);
        float2 w3[8];
        g8f(pk, w3);
#pragma unroll
        for (int e = 0; e < 8; ++e) {
          a0 += w3[e].x;
          a1 += w3[e].y;
        }
      }
    } else {
      const unsigned short* Bb = Min + jbase;
      auto g8 = [&](uint4 pk, unsigned* w) {
        w[0] = *(const unsigned*)(Bb + (size_t)(pk.x & 0xffff) * NMAT);
        w[1] = *(const unsigned*)(Bb + (size_t)(pk.x >> 16) * NMAT);
        w[2] = *(const unsigned*)(Bb + (size_t)(pk.y & 0xffff) * NMAT);
        w[3] = *(const unsigned*)(Bb + (size_t)(pk.y >> 16) * NMAT);
        w[4] = *(const unsigned*)(Bb + (size_t)(pk.z & 0xffff) * NMAT);
        w[5] = *(const unsigned*)(Bb + (size_t)(pk.z >> 16) * NMAT);
        w[6] = *(const unsigned*)(Bb + (size_t)(pk.w & 0xffff) * NMAT);
        w[7] = *(const unsigned*)(Bb + (size_t)(pk.w >> 16) * NMAT);
      };
      unsigned w[16];
      g8(pA, w);
      g8(pB, w + 8);
      bool more = nn > 16;
      unsigned w2[16];
      if (more) {
        g8(pC, w2);
        g8(pD, w2 + 8);
      }
#pragma unroll
      for (int e = 0; e < 16; ++e) {
        a0 += bflo(w[e]);
        a1 += bfhi(w[e]);
      }
      if (more) {
#pragma unroll
        for (int e = 0; e < 16; ++e) {
          a0 += bflo(w2[e]);
          a1 += bfhi(w2[e]);
        }
      }
      for (int t = 32; t < nn; t += 8) {
        uint4 pk = *(const uint4*)(ip + t);
        unsigned w3[8];
        g8(pk, w3);
#pragma unroll
        for (int e = 0; e < 8; ++e) {
          a0 += bflo(w3[e]);
          a1 += bfhi(w3[e]);
        }
      }
    }
    size_t o = (size_t)i * NMAT + jbase;
    __builtin_nontemporal_store(a0, T1 + o);
    __builtin_nontemporal_store(a1, T1 + o + 1);
  }
}

// --------------------------------------------------------------------------
// Phase B (v13): v12's Phase B verbatim; LDS tile filled from T1 (coalesced
// 32 KB/block) instead of computed in-place. Grid 512 x 1024.
// --------------------------------------------------------------------------
__global__ __launch_bounds__(1024, 8) void k_phB(
    const unsigned short* __restrict__ idx2T4, const int* __restrict__ cnt2,
    const float* __restrict__ T1, const unsigned* __restrict__ QM,
    const float* __restrict__ q, const float* __restrict__ Ht,
    unsigned short* __restrict__ Mout, float* __restrict__ MoutF,
    float* __restrict__ sout, int out32, int last) {
  __shared__ float lds[4 * NMAT + 64];
  const int GS = NMAT * 4;  // idx2T4 group stride (ushorts)
  int i0 = blockIdx.x * 4;
  int tid = threadIdx.x;  // 0..1023
  int c0 = tid * 2;       // this thread's 2 columns

  if (tid == 0) *(float4*)&lds[swz(SENT_B)] = make_float4(0.f, 0.f, 0.f, 0.f);

  // ---- load T1 tile -> LDS (transpose through registers) ----
  float2 r0 = *(const float2*)&T1[(size_t)(i0 + 0) * NMAT + c0];
  float2 r1 = *(const float2*)&T1[(size_t)(i0 + 1) * NMAT + c0];
  float2 r2 = *(const float2*)&T1[(size_t)(i0 + 2) * NMAT + c0];
  float2 r3 = *(const float2*)&T1[(size_t)(i0 + 3) * NMAT + c0];
  *(float4*)&lds[swz(c0)] = make_float4(r0.x, r1.x, r2.x, r3.x);
  *(float4*)&lds[swz(c0 + 1)] = make_float4(r0.y, r1.y, r2.y, r3.y);
  __syncthreads();

  // ---- Phase B: column gathers from LDS + epilogue ----
  const float alpha = 0.82f;
  const float oma = 1.0f - alpha;
#pragma unroll
  for (int jj = 0; jj < 2; ++jj) {
    int j = jj * 1024 + tid;
    int nn = cnt2[j];
    const unsigned short* bp = idx2T4 + j * 4;
    size_t off0 = (size_t)i0 * NMAT + j;
    // prefetch epilogue operands (hide under gather)
    unsigned wq0 = 0, wq1 = 0, wq2 = 0, wq3 = 0;
    if (!last) {
      wq0 = QM[off0];
      wq1 = QM[off0 + NMAT];
      wq2 = QM[off0 + 2 * NMAT];
      wq3 = QM[off0 + 3 * NMAT];
    }
    uint2 g0 = *(const uint2*)(bp);
    uint2 g1 = *(const uint2*)(bp + GS);
    uint2 g2 = *(const uint2*)(bp + 2 * GS);
    uint2 g3 = *(const uint2*)(bp + 3 * GS);
    float s0 = 0.f, s1 = 0.f, s2 = 0.f, s3 = 0.f;
    float u0 = 0.f, u1 = 0.f, u2 = 0.f, u3 = 0.f;
    {
      float4 va = *(const float4*)&lds[swz(g0.x & 0xffff)];
      float4 vb = *(const float4*)&lds[swz(g0.x >> 16)];
      float4 vc = *(const float4*)&lds[swz(g0.y & 0xffff)];
      float4 vd = *(const float4*)&lds[swz(g0.y >> 16)];
      float4 ve = *(const float4*)&lds[swz(g1.x & 0xffff)];
      float4 vf = *(const float4*)&lds[swz(g1.x >> 16)];
      float4 vg = *(const float4*)&lds[swz(g1.y & 0xffff)];
      float4 vh = *(const float4*)&lds[swz(g1.y >> 16)];
      s0 += (va.x + vb.x) + (vc.x + vd.x);
      s1 += (va.y + vb.y) + (vc.y + vd.y);
      s2 += (va.z + vb.z) + (vc.z + vd.z);
      s3 += (va.w + vb.w) + (vc.w + vd.w);
      u0 += (ve.x + vf.x) + (vg.x + vh.x);
      u1 += (ve.y + vf.y) + (vg.y + vh.y);
      u2 += (ve.z + vf.z) + (vg.z + vh.z);
      u3 += (ve.w + vf.w) + (vg.w + vh.w);
    }
    {
      float4 va = *(const float4*)&lds[swz(g2.x & 0xffff)];
      float4 vb = *(const float4*)&lds[swz(g2.x >> 16)];
      float4 vc = *(const float4*)&lds[swz(g2.y & 0xffff)];
      float4 vd = *(const float4*)&lds[swz(g2.y >> 16)];
      float4 ve = *(const float4*)&lds[swz(g3.x & 0xffff)];
      float4 vf = *(const float4*)&lds[swz(g3.x >> 16)];
      float4 vg = *(const float4*)&lds[swz(g3.y & 0xffff)];
      float4 vh = *(const float4*)&lds[swz(g3.y >> 16)];
      s0 += (va.x + vb.x) + (vc.x + vd.x);
      s1 += (va.y + vb.y) + (vc.y + vd.y);
      s2 += (va.z + vb.z) + (vc.z + vd.z);
      s3 += (va.w + vb.w) + (vc.w + vd.w);
      u0 += (ve.x + vf.x) + (vg.x + vh.x);
      u1 += (ve.y + vf.y) + (vg.y + vh.y);
      u2 += (ve.z + vf.z) + (vg.z + vh.z);
      u3 += (ve.w + vf.w) + (vg.w + vh.w);
    }
    for (int t = 16; t < nn; t += 8) {
      uint2 ga = *(const uint2*)(bp + (size_t)(t >> 2) * GS);
      uint2 gb = *(const uint2*)(bp + (size_t)((t >> 2) + 1) * GS);
      float4 va = *(const float4*)&lds[swz(ga.x & 0xffff)];
      float4 vb = *(const float4*)&lds[swz(ga.x >> 16)];
      float4 vc = *(const float4*)&lds[swz(ga.y & 0xffff)];
      float4 vd = *(const float4*)&lds[swz(ga.y >> 16)];
      float4 ve = *(const float4*)&lds[swz(gb.x & 0xffff)];
      float4 vf = *(const float4*)&lds[swz(gb.x >> 16)];
      float4 vg = *(const float4*)&lds[swz(gb.y & 0xffff)];
      float4 vh = *(const float4*)&lds[swz(gb.y >> 16)];
      s0 += (va.x + vb.x) + (vc.x + vd.x);
      s1 += (va.y + vb.y) + (vc.y + vd.y);
      s2 += (va.z + vb.z) + (vc.z + vd.z);
      s3 += (va.w + vb.w) + (vc.w + vd.w);
      u0 += (ve.x + vf.x) + (vg.x + vh.x);
      u1 += (ve.y + vf.y) + (vg.y + vh.y);
      u2 += (ve.z + vf.z) + (vg.z + vh.z);
      u3 += (ve.w + vf.w) + (vg.w + vh.w);
    }
    float sa[4] = {s0 + u0, s1 + u1, s2 + u2, s3 + u3};
    if (last) {
#pragma unroll
      for (int r = 0; r < 4; ++r) {
        size_t off = off0 + (size_t)r * NMAT;
        sout[off] = oma * Ht[off] + alpha * q[off] * sa[r];
      }
    } else if (out32) {
      MoutF[off0] = fmaf(bflo(wq0), sa[0], bfhi(wq0));
      MoutF[off0 + NMAT] = fmaf(bflo(wq1), sa[1], bfhi(wq1));
      MoutF[off0 + 2 * NMAT] = fmaf(bflo(wq2), sa[2], bfhi(wq2));
      MoutF[off0 + 3 * NMAT] = fmaf(bflo(wq3), sa[3], bfhi(wq3));
    } else {
      Mout[off0] = f2bf(fmaf(bflo(wq0), sa[0], bfhi(wq0)));
      Mout[off0 + NMAT] = f2bf(fmaf(bflo(wq1), sa[1], bfhi(wq1)));
      Mout[off0 + 2 * NMAT] = f2bf(fmaf(bflo(wq2), sa[2], bfhi(wq2)));
      Mout[off0 + 3 * NMAT] = f2bf(fmaf(bflo(wq3), sa[3], bfhi(wq3)));
    }
  }
}

extern "C" void kernel_launch(void* const* d_in, const int* in_sizes, int n_in,
                              void* d_out, int out_size, void* d_ws,
                              size_t ws_size, hipStream_t stream) {
  const float* A1 = (const float*)d_in[0];
  const float* A2 = (const float*)d_in[1];
  const float* N1 = (const float*)d_in[2];
  const float* N2 = (const float*)d_in[3];
  const float* H = (const float*)d_in[4];
  float* s_out = (float*)d_out;

  char* p = (char*)d_ws;
  auto take = [&](size_t bytes) {
    char* r = p;
    p += (bytes + 255) & ~(size_t)255;
    return r;
  };
  unsigned short* idx1 = (unsigned short*)take((size_t)NMAT * CAP * 2);
  unsigned short* idx2 = (unsigned short*)take((size_t)NMAT * CAP * 2);
  unsigned short* idx2T4 = (unsigned short*)take((size_t)CAP * NMAT * 2);
  int* cnt1 = (int*)take((size_t)NMAT * 4);
  int* cnt2 = (int*)take((size_t)NMAT * 4);
  float* N1n = (float*)take((size_t)NMAT * KATTR * 4);
  float* N2n = (float*)take((size_t)NMAT * KATTR * 4);
  float* C1 = (float*)take((size_t)NMAT * KATTR * 4);
  float* C2 = (float*)take((size_t)NMAT * KATTR * 4);
  float* Ht = (float*)take((size_t)NMAT * NMAT * 4);
  float* q = (float*)take((size_t)NMAT * NMAT * 4);
  unsigned* QM = (unsigned*)take((size_t)NMAT * NMAT * 4);
  float* T1 = (float*)take((size_t)NMAT * NMAT * 4);
  unsigned short* Mb0 = (unsigned short*)take((size_t)(NMAT + 1) * NMAT * 2);
  unsigned short* Mb1 = (unsigned short*)take((size_t)(NMAT + 1) * NMAT * 2);
  float* Mf = (float*)take((size_t)(NMAT + 1) * NMAT * 4);
  if ((size_t)(p - (char*)d_ws) > ws_size) return;

  k_build2<<<2 * NMAT, 256, 0, stream>>>(A1, A2, idx1, idx2, idx2T4, cnt1,
                                         cnt2);
  k_norm2<<<2 * (NMAT / 4), 256, 0, stream>>>(N1, N2, N1n, N2n);
  k_gatherN2<<<2 * NMAT, 64, 0, stream>>>(idx1, cnt1, N1n, C1, idx2, cnt2,
                                          N2n, C2);
  k_q<<<dim3(32, 32), 256, 0, stream>>>(N1n, C1, N2n, C2, H, q, QM, Mb0, Ht);
  k_zrow<<<1, 1024, 0, stream>>>(Mb0, Mb1, Mf);
  for (int it = 0; it < NITER; ++it) {
    const unsigned short* Min = (it & 1) ? Mb1 : Mb0;
    unsigned short* Mout = (it & 1) ? Mb0 : Mb1;
    int in32 = (it == NITER - 1) ? 1 : 0;
    int out32 = (it == NITER - 2) ? 1 : 0;
    int last = (it == NITER - 1) ? 1 : 0;
    k_phA<<<NMAT / 4, 1024, 0, stream>>>(idx1, cnt1, Min, Mf, T1, in32);
    k_phB<<<NMAT / 4, 1024, 0, stream>>>(idx2T4, cnt2, T1, QM, q, Ht, Mout,
                                         Mf, s_out, out32, last);
  }
}

// Round 13
// 400.317 us; speedup vs baseline: 1.4048x; 1.4048x over previous
//
#include <hip/hip_runtime.h>

#define NMAT 2048
#define KATTR 64
#define CAP 64
#define NITER 10
#define SENT_A 2048  // Phase A sentinel: extra zeroed row of M buffers
#define SENT_B 2057  // Phase B sentinel: swz(2057)=8232, outside real swz image

typedef unsigned short ushort4v __attribute__((ext_vector_type(4)));

__device__ __forceinline__ unsigned short f2bf(float f) {
  unsigned u = __float_as_uint(f);
  return (unsigned short)((u + 0x7fff + ((u >> 16) & 1)) >> 16);
}
__device__ __forceinline__ float bf2f(unsigned short b) {
  return __uint_as_float((unsigned)b << 16);
}
__device__ __forceinline__ float bflo(unsigned v) {
  return __uint_as_float(v << 16);
}
__device__ __forceinline__ float bfhi(unsigned v) {
  return __uint_as_float(v & 0xffff0000u);
}
// swizzled LDS dword index (proven v3/v5/v7)
__device__ __forceinline__ int swz(int c) { return 4 * c + (((c >> 3) & 7) << 2); }

// --------------------------------------------------------------------------
// DETERMINISTIC build: count -> scan -> write in ascending column order.
// Grid 2*NMAT: b < NMAT: A1 row (no idxT4); b >= NMAT: A2 row (+ idxT4).
// --------------------------------------------------------------------------
__global__ __launch_bounds__(256) void k_build2(
    const float* __restrict__ A1, const float* __restrict__ A2,
    unsigned short* __restrict__ idx1, unsigned short* __restrict__ idx2,
    unsigned short* __restrict__ idxT4, int* __restrict__ cnt1,
    int* __restrict__ cnt2) {
  __shared__ int wsum[4];
  int b = blockIdx.x;
  const float* A;
  unsigned short* idx;
  unsigned short* idxT;
  int* cnt;
  int r;
  if (b < NMAT) {
    A = A1; idx = idx1; idxT = nullptr; cnt = cnt1; r = b;
  } else {
    A = A2; idx = idx2; idxT = idxT4; cnt = cnt2; r = b - NMAT;
  }
  const float* row = A + (size_t)r * NMAT;
  int t = threadIdx.x;
  unsigned mask = 0;
  int ln = 0;
#pragma unroll
  for (int u = 0; u < 8; ++u) {
    int c = t * 8 + u;
    if (row[c] != 0.0f) {
      mask |= 1u << u;
      ++ln;
    }
  }
  int lane = t & 63, wv = t >> 6;
  int v = ln;
  for (int o = 1; o < 64; o <<= 1) {
    int x = __shfl_up(v, o);
    if (lane >= o) v += x;
  }
  if (lane == 63) wsum[wv] = v;
  __syncthreads();
  int base = 0, stot = 0;
#pragma unroll
  for (int w = 0; w < 4; ++w) {
    int x = wsum[w];
    if (w < wv) base += x;
    stot += x;
  }
  int off = base + v - ln;
#pragma unroll
  for (int u = 0; u < 8; ++u) {
    if (mask & (1u << u)) {
      int c = t * 8 + u;
      if (off < CAP) {
        idx[r * CAP + off] = (unsigned short)c;
        if (idxT)
          idxT[(size_t)(off >> 2) * (NMAT * 4) + r * 4 + (off & 3)] =
              (unsigned short)c;
      }
      ++off;
    }
  }
  int n = stot < CAP ? stot : CAP;
  for (int p = n + t; p < CAP; p += 256) {
    idx[r * CAP + p] = (unsigned short)SENT_A;
    if (idxT)
      idxT[(size_t)(p >> 2) * (NMAT * 4) + r * 4 + (p & 3)] =
          (unsigned short)SENT_B;
  }
  if (t == 0) cnt[r] = n;
}

// Row-l2-normalize N1 and N2 in one launch (grid 2*(NMAT/4)).
__global__ __launch_bounds__(256) void k_norm2(const float* __restrict__ N1,
                                               const float* __restrict__ N2,
                                               float* __restrict__ N1n,
                                               float* __restrict__ N2n) {
  int half = blockIdx.x >= (NMAT / 4);
  const float* Nin = half ? N2 : N1;
  float* Nout = half ? N2n : N1n;
  int bb = half ? blockIdx.x - NMAT / 4 : blockIdx.x;
  int row = bb * 4 + (threadIdx.x >> 6);
  int lane = threadIdx.x & 63;
  float v = Nin[(size_t)row * KATTR + lane];
  float ss = v * v;
#pragma unroll
  for (int o = 32; o > 0; o >>= 1) ss += __shfl_xor(ss, o);
  float nrm = sqrtf(ss);
  Nout[(size_t)row * KATTR + lane] = (nrm > 0.f) ? v / nrm : 0.f;
}

// C1 = pattern(A1) @ N1n and C2 = pattern(A2) @ N2n in one launch.
__global__ void k_gatherN2(const unsigned short* __restrict__ idx1,
                           const int* __restrict__ cnt1,
                           const float* __restrict__ N1n,
                           float* __restrict__ C1,
                           const unsigned short* __restrict__ idx2,
                           const int* __restrict__ cnt2,
                           const float* __restrict__ N2n,
                           float* __restrict__ C2) {
  int half = blockIdx.x >= NMAT;
  const unsigned short* idx = half ? idx2 : idx1;
  const int* cnt = half ? cnt2 : cnt1;
  const float* Nn = half ? N2n : N1n;
  float* C = half ? C2 : C1;
  int i = half ? blockIdx.x - NMAT : blockIdx.x;
  int lane = threadIdx.x;  // blockDim = 64
  int nn = cnt[i];
  const unsigned short* ip = idx + i * CAP;
  float acc = 0.f;
  for (int t = 0; t < nn; ++t) {
    int k = ip[t];
    acc += Nn[(size_t)k * KATTR + lane];
  }
  C[(size_t)i * KATTR + lane] = acc;
}

// Zero the sentinel row (row 2048) of the gather buffers, once.
__global__ __launch_bounds__(1024) void k_zrow(unsigned short* __restrict__ Mb0,
                                               unsigned short* __restrict__ Mb1,
                                               float* __restrict__ Mf) {
  size_t Z = (size_t)NMAT * NMAT;
  for (int o = threadIdx.x; o < NMAT; o += 1024) {
    Mb0[Z + o] = 0;
    Mb1[Z + o] = 0;
    Mf[Z + o] = 0.f;
  }
}

// --------------------------------------------------------------------------
// q = Nm>0&dm>0 ? Nm*rsqrt(Nm*dm) : 0.   (H-transpose fused through LDS;
// also emits Ht for the last-iteration fp32 epilogue.)
// v14: 512 threads/block (was 256) — v13's profile showed k_q at 46 us,
// 26% occupancy (grid 1024 x 4 waves = 16 waves/CU cap, latency-bound).
// 512 thr -> 8 waves/block x 4 blocks/CU = 32 waves/CU cap. Each thread
// now computes a 2x4 micro-tile; per-output k-accumulation order is
// UNCHANGED -> bit-identical results (determinism + absmax preserved).
// --------------------------------------------------------------------------
__global__ __launch_bounds__(512) void k_q(
    const float* __restrict__ N1n, const float* __restrict__ C1,
    const float* __restrict__ N2n, const float* __restrict__ C2,
    const float* __restrict__ H, float* __restrict__ q,
    unsigned* __restrict__ QM, unsigned short* __restrict__ M,
    float* __restrict__ Ht) {
  __shared__ float sA[64][68];
  __shared__ float sB[64][68];
  int i0 = blockIdx.y * 64, j0 = blockIdx.x * 64;
  int c = threadIdx.x & 63, r0 = threadIdx.x >> 6;   // stage: 8 rows/thread
  int tx = threadIdx.x & 15, ty = threadIdx.x >> 4;  // ty 0..31: 2 rows each
  const float alpha = 0.82f;

  float nmv[2][4] = {};
  float dmv[2][4] = {};

  for (int r = r0; r < 64; r += 8) {
    sA[c][r] = N1n[(size_t)(i0 + r) * KATTR + c];
    sB[c][r] = N2n[(size_t)(j0 + r) * KATTR + c];
  }
  __syncthreads();
#pragma unroll 4
  for (int k = 0; k < 64; ++k) {
    float2 a = *(const float2*)&sA[k][ty * 2];
    float4 b = *(const float4*)&sB[k][tx * 4];
    float av[2] = {a.x, a.y};
    float bv[4] = {b.x, b.y, b.z, b.w};
#pragma unroll
    for (int ii = 0; ii < 2; ++ii)
#pragma unroll
      for (int jj = 0; jj < 4; ++jj)
        nmv[ii][jj] = fmaf(av[ii], bv[jj], nmv[ii][jj]);
  }
  __syncthreads();
  for (int r = r0; r < 64; r += 8) {
    sA[c][r] = C1[(size_t)(i0 + r) * KATTR + c];
    sB[c][r] = C2[(size_t)(j0 + r) * KATTR + c];
  }
  __syncthreads();
#pragma unroll 4
  for (int k = 0; k < 64; ++k) {
    float2 a = *(const float2*)&sA[k][ty * 2];
    float4 b = *(const float4*)&sB[k][tx * 4];
    float av[2] = {a.x, a.y};
    float bv[4] = {b.x, b.y, b.z, b.w};
#pragma unroll
    for (int ii = 0; ii < 2; ++ii)
#pragma unroll
      for (int jj = 0; jj < 4; ++jj)
        dmv[ii][jj] = fmaf(av[ii], bv[jj], dmv[ii][jj]);
  }
  __syncthreads();
  // fused transpose: sA[i_local][j_local] = H[(j0+j_local)*NMAT + i0+i_local]
  for (int r = r0; r < 64; r += 8)
    sA[c][r] = H[(size_t)(j0 + r) * NMAT + i0 + c];
  __syncthreads();

#pragma unroll
  for (int ii = 0; ii < 2; ++ii) {
    int i = i0 + ty * 2 + ii;
    size_t base = (size_t)i * NMAT + j0 + tx * 4;
    float4 hv = *(const float4*)&sA[ty * 2 + ii][tx * 4];
    float hvv[4] = {hv.x, hv.y, hv.z, hv.w};
    float qv[4];
    unsigned qmv[4];
    ushort4v mv;
#pragma unroll
    for (int jj = 0; jj < 4; ++jj) {
      float nmx = nmv[ii][jj];
      float D = nmx * dmv[ii][jj];
      float qq = (D > 0.f) ? nmx * rsqrtf(D) : 0.f;
      qv[jj] = qq;
      float m0 = qq * hvv[jj];
      mv[jj] = f2bf(m0);
      qmv[jj] = (unsigned)f2bf(alpha * qq * qq) |
                ((unsigned)f2bf((1.0f - alpha) * m0) << 16);
    }
    *(float4*)&q[base] = make_float4(qv[0], qv[1], qv[2], qv[3]);
    *(uint4*)&QM[base] = make_uint4(qmv[0], qmv[1], qmv[2], qmv[3]);
    *(ushort4v*)&M[base] = mv;
    *(float4*)&Ht[base] = hv;
  }
}

// --------------------------------------------------------------------------
// One full iteration, fused (k_iter = v5/v12 VERBATIM — measured best; v8
// k-sort, v9 sw-pipeline, v13 XCD-pinned split all regressed).
// Grid 512 x 1024 (16 waves/block, 2 blocks/CU = 32 waves/CU).
// --------------------------------------------------------------------------
__global__ __launch_bounds__(1024, 8) void k_iter(
    const unsigned short* __restrict__ idx1, const int* __restrict__ cnt1,
    const unsigned short* __restrict__ idx2T4, const int* __restrict__ cnt2,
    const unsigned short* __restrict__ Min, const float* __restrict__ MinF,
    const unsigned* __restrict__ QM, const float* __restrict__ q,
    const float* __restrict__ Ht, unsigned short* __restrict__ Mout,
    float* __restrict__ MoutF, float* __restrict__ sout, int in32, int out32,
    int last) {
  __shared__ float lds[4 * NMAT + 64];
  const int GS = NMAT * 4;  // idx2T4 group stride (ushorts)
  int i0 = blockIdx.x * 4;
  int tid = threadIdx.x;  // 0..1023
  int c0 = tid * 2;       // this thread's 2 columns

  if (tid == 0) *(float4*)&lds[swz(SENT_B)] = make_float4(0.f, 0.f, 0.f, 0.f);

  // ---- Phase A: row gathers ----
  float acc[4][2];
#pragma unroll
  for (int r = 0; r < 4; ++r) {
    int nn = cnt1[i0 + r];
    const unsigned short* ip = idx1 + (i0 + r) * CAP;
    // whole-row index preload (sentinel-padded, always valid)
    uint4 pA = *(const uint4*)(ip);
    uint4 pB = *(const uint4*)(ip + 8);
    uint4 pC = *(const uint4*)(ip + 16);
    uint4 pD = *(const uint4*)(ip + 24);
    float a0 = 0.f, a1 = 0.f;
    if (in32) {
      const float* Bf = MinF + c0;
      auto g8f = [&](uint4 pk, float2* w) {
        w[0] = *(const float2*)(Bf + (size_t)(pk.x & 0xffff) * NMAT);
        w[1] = *(const float2*)(Bf + (size_t)(pk.x >> 16) * NMAT);
        w[2] = *(const float2*)(Bf + (size_t)(pk.y & 0xffff) * NMAT);
        w[3] = *(const float2*)(Bf + (size_t)(pk.y >> 16) * NMAT);
        w[4] = *(const float2*)(Bf + (size_t)(pk.z & 0xffff) * NMAT);
        w[5] = *(const float2*)(Bf + (size_t)(pk.z >> 16) * NMAT);
        w[6] = *(const float2*)(Bf + (size_t)(pk.w & 0xffff) * NMAT);
        w[7] = *(const float2*)(Bf + (size_t)(pk.w >> 16) * NMAT);
      };
      float2 w[16];
      g8f(pA, w);
      g8f(pB, w + 8);
#pragma unroll
      for (int e = 0; e < 16; ++e) {
        a0 += w[e].x;
        a1 += w[e].y;
      }
      if (nn > 16) {
        float2 w2[16];
        g8f(pC, w2);
        g8f(pD, w2 + 8);
#pragma unroll
        for (int e = 0; e < 16; ++e) {
          a0 += w2[e].x;
          a1 += w2[e].y;
        }
      }
      for (int t = 32; t < nn; t += 8) {
        uint4 pk = *(const uint4*)(ip + t);
        float2 w3[8];
        g8f(pk, w3);
#pragma unroll
        for (int e = 0; e < 8; ++e) {
          a0 += w3[e].x;
          a1 += w3[e].y;
        }
      }
    } else {
      const unsigned short* Bb = Min + c0;
      auto g8 = [&](uint4 pk, unsigned* w) {
        w[0] = *(const unsigned*)(Bb + (size_t)(pk.x & 0xffff) * NMAT);
        w[1] = *(const unsigned*)(Bb + (size_t)(pk.x >> 16) * NMAT);
        w[2] = *(const unsigned*)(Bb + (size_t)(pk.y & 0xffff) * NMAT);
        w[3] = *(const unsigned*)(Bb + (size_t)(pk.y >> 16) * NMAT);
        w[4] = *(const unsigned*)(Bb + (size_t)(pk.z & 0xffff) * NMAT);
        w[5] = *(const unsigned*)(Bb + (size_t)(pk.z >> 16) * NMAT);
        w[6] = *(const unsigned*)(Bb + (size_t)(pk.w & 0xffff) * NMAT);
        w[7] = *(const unsigned*)(Bb + (size_t)(pk.w >> 16) * NMAT);
      };
      unsigned w[16];
      g8(pA, w);
      g8(pB, w + 8);
      bool more = nn > 16;
      unsigned w2[16];
      if (more) {
        g8(pC, w2);
        g8(pD, w2 + 8);
      }
#pragma unroll
      for (int e = 0; e < 16; ++e) {
        a0 += bflo(w[e]);
        a1 += bfhi(w[e]);
      }
      if (more) {
#pragma unroll
        for (int e = 0; e < 16; ++e) {
          a0 += bflo(w2[e]);
          a1 += bfhi(w2[e]);
        }
      }
      for (int t = 32; t < nn; t += 8) {
        uint4 pk = *(const uint4*)(ip + t);
        unsigned w3[8];
        g8(pk, w3);
#pragma unroll
        for (int e = 0; e < 8; ++e) {
          a0 += bflo(w3[e]);
          a1 += bfhi(w3[e]);
        }
      }
    }
    acc[r][0] = a0;
    acc[r][1] = a1;
  }
  *(float4*)&lds[swz(c0)] =
      make_float4(acc[0][0], acc[1][0], acc[2][0], acc[3][0]);
  *(float4*)&lds[swz(c0 + 1)] =
      make_float4(acc[0][1], acc[1][1], acc[2][1], acc[3][1]);
  __syncthreads();

  // ---- Phase B: column gathers from LDS + epilogue ----
  const float alpha = 0.82f;
  const float oma = 1.0f - alpha;
#pragma unroll
  for (int jj = 0; jj < 2; ++jj) {
    int j = jj * 1024 + tid;
    int nn = cnt2[j];
    const unsigned short* bp = idx2T4 + j * 4;
    size_t off0 = (size_t)i0 * NMAT + j;
    // prefetch epilogue operands (hide under gather)
    unsigned wq0 = 0, wq1 = 0, wq2 = 0, wq3 = 0;
    if (!last) {
      wq0 = QM[off0];
      wq1 = QM[off0 + NMAT];
      wq2 = QM[off0 + 2 * NMAT];
      wq3 = QM[off0 + 3 * NMAT];
    }
    // first 16 edges unconditionally (sentinel slots are zeroed broadcast)
    uint2 g0 = *(const uint2*)(bp);
    uint2 g1 = *(const uint2*)(bp + GS);
    uint2 g2 = *(const uint2*)(bp + 2 * GS);
    uint2 g3 = *(const uint2*)(bp + 3 * GS);
    float s0 = 0.f, s1 = 0.f, s2 = 0.f, s3 = 0.f;
    float u0 = 0.f, u1 = 0.f, u2 = 0.f, u3 = 0.f;
    {
      float4 va = *(const float4*)&lds[swz(g0.x & 0xffff)];
      float4 vb = *(const float4*)&lds[swz(g0.x >> 16)];
      float4 vc = *(const float4*)&lds[swz(g0.y & 0xffff)];
      float4 vd = *(const float4*)&lds[swz(g0.y >> 16)];
      float4 ve = *(const float4*)&lds[swz(g1.x & 0xffff)];
      float4 vf = *(const float4*)&lds[swz(g1.x >> 16)];
      float4 vg = *(const float4*)&lds[swz(g1.y & 0xffff)];
      float4 vh = *(const float4*)&lds[swz(g1.y >> 16)];
      s0 += (va.x + vb.x) + (vc.x + vd.x);
      s1 += (va.y + vb.y) + (vc.y + vd.y);
      s2 += (va.z + vb.z) + (vc.z + vd.z);
      s3 += (va.w + vb.w) + (vc.w + vd.w);
      u0 += (ve.x + vf.x) + (vg.x + vh.x);
      u1 += (ve.y + vf.y) + (vg.y + vh.y);
      u2 += (ve.z + vf.z) + (vg.z + vh.z);
      u3 += (ve.w + vf.w) + (vg.w + vh.w);
    }
    {
      float4 va = *(const float4*)&lds[swz(g2.x & 0xffff)];
      float4 vb = *(const float4*)&lds[swz(g2.x >> 16)];
      float4 vc = *(const float4*)&lds[swz(g2.y & 0xffff)];
      float4 vd = *(const float4*)&lds[swz(g2.y >> 16)];
      float4 ve = *(const float4*)&lds[swz(g3.x & 0xffff)];
      float4 vf = *(const float4*)&lds[swz(g3.x >> 16)];
      float4 vg = *(const float4*)&lds[swz(g3.y & 0xffff)];
      float4 vh = *(const float4*)&lds[swz(g3.y >> 16)];
      s0 += (va.x + vb.x) + (vc.x + vd.x);
      s1 += (va.y + vb.y) + (vc.y + vd.y);
      s2 += (va.z + vb.z) + (vc.z + vd.z);
      s3 += (va.w + vb.w) + (vc.w + vd.w);
      u0 += (ve.x + vf.x) + (vg.x + vh.x);
      u1 += (ve.y + vf.y) + (vg.y + vh.y);
      u2 += (ve.z + vf.z) + (vg.z + vh.z);
      u3 += (ve.w + vf.w) + (vg.w + vh.w);
    }
    for (int t = 16; t < nn; t += 8) {
      uint2 ga = *(const uint2*)(bp + (size_t)(t >> 2) * GS);
      uint2 gb = *(const uint2*)(bp + (size_t)((t >> 2) + 1) * GS);
      float4 va = *(const float4*)&lds[swz(ga.x & 0xffff)];
      float4 vb = *(const float4*)&lds[swz(ga.x >> 16)];
      float4 vc = *(const float4*)&lds[swz(ga.y & 0xffff)];
      float4 vd = *(const float4*)&lds[swz(ga.y >> 16)];
      float4 ve = *(const float4*)&lds[swz(gb.x & 0xffff)];
      float4 vf = *(const float4*)&lds[swz(gb.x >> 16)];
      float4 vg = *(const float4*)&lds[swz(gb.y & 0xffff)];
      float4 vh = *(const float4*)&lds[swz(gb.y >> 16)];
      s0 += (va.x + vb.x) + (vc.x + vd.x);
      s1 += (va.y + vb.y) + (vc.y + vd.y);
      s2 += (va.z + vb.z) + (vc.z + vd.z);
      s3 += (va.w + vb.w) + (vc.w + vd.w);
      u0 += (ve.x + vf.x) + (vg.x + vh.x);
      u1 += (ve.y + vf.y) + (vg.y + vh.y);
      u2 += (ve.z + vf.z) + (vg.z + vh.z);
      u3 += (ve.w + vf.w) + (vg.w + vh.w);
    }
    float sa[4] = {s0 + u0, s1 + u1, s2 + u2, s3 + u3};
    if (last) {
#pragma unroll
      for (int r = 0; r < 4; ++r) {
        size_t off = off0 + (size_t)r * NMAT;
        sout[off] = oma * Ht[off] + alpha * q[off] * sa[r];
      }
    } else if (out32) {
      MoutF[off0] = fmaf(bflo(wq0), sa[0], bfhi(wq0));
      MoutF[off0 + NMAT] = fmaf(bflo(wq1), sa[1], bfhi(wq1));
      MoutF[off0 + 2 * NMAT] = fmaf(bflo(wq2), sa[2], bfhi(wq2));
      MoutF[off0 + 3 * NMAT] = fmaf(bflo(wq3), sa[3], bfhi(wq3));
    } else {
      Mout[off0] = f2bf(fmaf(bflo(wq0), sa[0], bfhi(wq0)));
      Mout[off0 + NMAT] = f2bf(fmaf(bflo(wq1), sa[1], bfhi(wq1)));
      Mout[off0 + 2 * NMAT] = f2bf(fmaf(bflo(wq2), sa[2], bfhi(wq2)));
      Mout[off0 + 3 * NMAT] = f2bf(fmaf(bflo(wq3), sa[3], bfhi(wq3)));
    }
  }
}

extern "C" void kernel_launch(void* const* d_in, const int* in_sizes, int n_in,
                              void* d_out, int out_size, void* d_ws,
                              size_t ws_size, hipStream_t stream) {
  const float* A1 = (const float*)d_in[0];
  const float* A2 = (const float*)d_in[1];
  const float* N1 = (const float*)d_in[2];
  const float* N2 = (const float*)d_in[3];
  const float* H = (const float*)d_in[4];
  float* s_out = (float*)d_out;

  char* p = (char*)d_ws;
  auto take = [&](size_t bytes) {
    char* r = p;
    p += (bytes + 255) & ~(size_t)255;
    return r;
  };
  unsigned short* idx1 = (unsigned short*)take((size_t)NMAT * CAP * 2);
  unsigned short* idx2 = (unsigned short*)take((size_t)NMAT * CAP * 2);
  unsigned short* idx2T4 = (unsigned short*)take((size_t)CAP * NMAT * 2);
  int* cnt1 = (int*)take((size_t)NMAT * 4);
  int* cnt2 = (int*)take((size_t)NMAT * 4);
  float* N1n = (float*)take((size_t)NMAT * KATTR * 4);
  float* N2n = (float*)take((size_t)NMAT * KATTR * 4);
  float* C1 = (float*)take((size_t)NMAT * KATTR * 4);
  float* C2 = (float*)take((size_t)NMAT * KATTR * 4);
  float* Ht = (float*)take((size_t)NMAT * NMAT * 4);
  float* q = (float*)take((size_t)NMAT * NMAT * 4);
  unsigned* QM = (unsigned*)take((size_t)NMAT * NMAT * 4);
  unsigned short* Mb0 = (unsigned short*)take((size_t)(NMAT + 1) * NMAT * 2);
  unsigned short* Mb1 = (unsigned short*)take((size_t)(NMAT + 1) * NMAT * 2);
  float* Mf = (float*)take((size_t)(NMAT + 1) * NMAT * 4);
  if ((size_t)(p - (char*)d_ws) > ws_size) return;

  k_build2<<<2 * NMAT, 256, 0, stream>>>(A1, A2, idx1, idx2, idx2T4, cnt1,
                                         cnt2);
  k_norm2<<<2 * (NMAT / 4), 256, 0, stream>>>(N1, N2, N1n, N2n);
  k_gatherN2<<<2 * NMAT, 64, 0, stream>>>(idx1, cnt1, N1n, C1, idx2, cnt2,
                                          N2n, C2);
  k_q<<<dim3(32, 32), 512, 0, stream>>>(N1n, C1, N2n, C2, H, q, QM, Mb0, Ht);
  k_zrow<<<1, 1024, 0, stream>>>(Mb0, Mb1, Mf);
  for (int it = 0; it < NITER; ++it) {
    const unsigned short* Min = (it & 1) ? Mb1 : Mb0;
    unsigned short* Mout = (it & 1) ? Mb0 : Mb1;
    int in32 = (it == NITER - 1) ? 1 : 0;
    int out32 = (it == NITER - 2) ? 1 : 0;
    int last = (it == NITER - 1) ? 1 : 0;
    k_iter<<<NMAT / 4, 1024, 0, stream>>>(idx1, cnt1, idx2T4, cnt2, Min, Mf,
                                          QM, q, Ht, Mout, Mf, s_out, in32,
                                          out32, last);
  }
}